// Round 17
// baseline (636.987 us; speedup 1.0000x reference)
//
#include <hip/hip_runtime.h>

#define NN 50000
#define EE 800000
#define FIN 16
#define EDIM 4
#define EMB 32
#define NH 4
#define HC 128          // EMB*NH
#define NL 2
#define DENSE 128
#define QNPB 50         // nodes per qkvs/ftq/head block (50000 = 1000 * 50)
#define SBLK 49         // scan blocks: ceil(50000/1024)

// unpack two packed fp16 -> float2
__device__ __forceinline__ float2 h2f2(unsigned int u) {
    union { unsigned int u; _Float16 h[2]; } c; c.u = u;
    return make_float2((float)c.h[0], (float)c.h[1]);
}
__device__ __forceinline__ unsigned int pkh2(float a, float b) {
    union { unsigned int u; _Float16 h[2]; } c;
    c.h[0] = (_Float16)a; c.h[1] = (_Float16)b; return c.u;
}

// ---------------- CSR build ----------------
__global__ void hist_kernel(const int* __restrict__ dst, int* __restrict__ counts) {
    int e = blockIdx.x * blockDim.x + threadIdx.x;
    if (e < EE) atomicAdd(&counts[dst[e]], 1);
}

__global__ __launch_bounds__(1024) void scan1_kernel(const int* __restrict__ cursor,
                                                     int* __restrict__ row_ptr,
                                                     int* __restrict__ bsum) {
    __shared__ int wsum[16];
    __shared__ int wpre[17];
    int tid = threadIdx.x, lane = tid & 63, wid = tid >> 6;
    int i = blockIdx.x * 1024 + tid;
    int v = (i < NN) ? cursor[i] : 0;
    int incl = v;
    #pragma unroll
    for (int off = 1; off < 64; off <<= 1) {
        int t = __shfl_up(incl, off, 64);
        if (lane >= off) incl += t;
    }
    if (lane == 63) wsum[wid] = incl;
    __syncthreads();
    if (tid == 0) {
        int acc = 0;
        #pragma unroll
        for (int w = 0; w < 16; ++w) { wpre[w] = acc; acc += wsum[w]; }
        wpre[16] = acc;
    }
    __syncthreads();
    if (i < NN) row_ptr[i] = wpre[wid] + incl - v;
    if (tid == 0) bsum[blockIdx.x] = wpre[16];
}

// scan3 with scan2 folded in: every block re-scans the 49 block sums in its first wave
__global__ __launch_bounds__(1024) void scan3_kernel(int* __restrict__ row_ptr,
                                                     int* __restrict__ cursor,
                                                     const int* __restrict__ bsum) {
    __shared__ int boff_s;
    __shared__ int total_s;
    int tid = threadIdx.x;
    if (tid < 64) {
        int v = (tid < SBLK) ? bsum[tid] : 0;
        int incl = v;
        #pragma unroll
        for (int off = 1; off < 64; off <<= 1) {
            int u = __shfl_up(incl, off, 64);
            if (tid >= off) incl += u;
        }
        if (tid == (int)blockIdx.x) boff_s = incl - v;
        if (tid == 63) total_s = incl;
    }
    __syncthreads();
    int i = blockIdx.x * 1024 + tid;
    if (i < NN) {
        int r = row_ptr[i] + boff_s;
        row_ptr[i] = r;
        cursor[i] = r;
    }
    if (blockIdx.x == 0 && tid == 0) row_ptr[NN] = total_s;   // == EE
}

// edge record: x=src, y=ea fp16(0,1), z=ea fp16(2,3), w=unused — one 16B store
__global__ void scatter_kernel(const int* __restrict__ src, const int* __restrict__ dst,
                               const float* __restrict__ ea, int* __restrict__ cursor,
                               uint4* __restrict__ edges) {
    int e = blockIdx.x * blockDim.x + threadIdx.x;
    if (e >= EE) return;
    int d = dst[e];
    int pos = atomicAdd(&cursor[d], 1);
    float4 q = *reinterpret_cast<const float4*>(ea + (size_t)e * 4);
    uint4 rec;
    rec.x = (unsigned int)src[e];
    rec.y = pkh2(q.x, q.y);
    rec.z = pkh2(q.z, q.w);
    rec.w = 0u;
    edges[pos] = rec;
}

// ------- layer-0 projections: 2 matrices per thread (m2=0: K+V, m2=1: Q+S) ----------
__global__ __launch_bounds__(512) void qkvs0_kernel(const float* __restrict__ x,
        const float* __restrict__ Wq, const float* __restrict__ bq,
        const float* __restrict__ Wk, const float* __restrict__ bk,
        const float* __restrict__ Wv, const float* __restrict__ bv,
        const float* __restrict__ Ws, const float* __restrict__ bs,
        _Float16* __restrict__ Qh, unsigned int* __restrict__ kvu,
        float* __restrict__ Out) {
    __shared__ __align__(16) float hs[QNPB * FIN];
    int tid = threadIdx.x;
    int c = tid & 127;
    int m2 = tid >> 8;            // 0: K+V (one packed store), 1: Q+S
    int g2 = (tid >> 7) & 1;      // node subgroup
    const float *Wa, *ba, *Wb, *bb;
    if (m2 == 0) { Wa = Wk; ba = bk; Wb = Wv; bb = bv; }
    else         { Wa = Wq; ba = bq; Wb = Ws; bb = bs; }
    float wa[FIN], wb[FIN];
    #pragma unroll
    for (int f = 0; f < FIN; ++f) { wa[f] = Wa[f * HC + c]; wb[f] = Wb[f * HC + c]; }
    float ba_ = ba[c], bb_ = bb[c];
    int node0 = blockIdx.x * QNPB;
    {   // float4 staging copy
        const float4* src4 = (const float4*)(x + (size_t)node0 * FIN);
        float4* dst4 = (float4*)hs;
        for (int i = tid; i < QNPB * FIN / 4; i += 512) dst4[i] = src4[i];
    }
    __syncthreads();
    for (int k = g2; k < QNPB; k += 2) {
        const float4* h4 = (const float4*)(hs + k * FIN);
        float sa = ba_, sb = bb_;
        #pragma unroll
        for (int f4 = 0; f4 < FIN / 4; ++f4) {
            float4 hv = h4[f4];
            sa += hv.x * wa[4*f4] + hv.y * wa[4*f4+1] + hv.z * wa[4*f4+2] + hv.w * wa[4*f4+3];
            sb += hv.x * wb[4*f4] + hv.y * wb[4*f4+1] + hv.z * wb[4*f4+2] + hv.w * wb[4*f4+3];
        }
        size_t n = node0 + k;
        if (m2 == 0) kvu[n * 128 + c] = pkh2(sa, sb);          // (k,v) one store
        else { Qh[n * HC + c] = (_Float16)sa; Out[n * HC + c] = sb; }
    }
}

// ---- fused transform + projections: reg Wt stage T + dual-matrix QKVS ---------------
__global__ __launch_bounds__(512) void ftq_kernel(const float* __restrict__ Wt,
        const float* __restrict__ bt,
        const float* __restrict__ Wq, const float* __restrict__ bq,
        const float* __restrict__ Wk, const float* __restrict__ bk,
        const float* __restrict__ Wv, const float* __restrict__ bv,
        const float* __restrict__ Ws, const float* __restrict__ bs,
        _Float16* __restrict__ Qh, unsigned int* __restrict__ kvu,
        float* __restrict__ Out) {
    __shared__ __align__(16) float os[QNPB * HC];   // 25.6 KB
    __shared__ __align__(16) float hs[QNPB * EMB];  // 6.4 KB
    int tid = threadIdx.x;
    int node0 = blockIdx.x * QNPB;
    int g = tid >> 7;                   // 4 node-groups (2 waves each)

    {   // float4 staging copy
        const float4* src4 = (const float4*)(Out + (size_t)node0 * HC);
        float4* dst4 = (float4*)os;
        for (int i = tid; i < QNPB * HC / 4; i += 512) dst4[i] = src4[i];
    }

    // stage T: h = relu(bt + Out @ Wt). thread (g, cT=(tid&127)>>2, seg=tid&3)
    int cT = (tid & 127) >> 2, seg = tid & 3;
    float wt[32];
    #pragma unroll
    for (int j = 0; j < 32; ++j) wt[j] = Wt[(seg * 32 + j) * EMB + cT];
    float btc = bt[cT];
    __syncthreads();
    for (int k = g; k < QNPB; k += 4) {
        float p = 0.f;
        const float4* r4 = (const float4*)(os + k * HC + seg * 32);
        #pragma unroll
        for (int j4 = 0; j4 < 8; ++j4) {
            float4 rv = r4[j4];
            p += rv.x * wt[4 * j4] + rv.y * wt[4 * j4 + 1]
               + rv.z * wt[4 * j4 + 2] + rv.w * wt[4 * j4 + 3];
        }
        p += __shfl_xor(p, 1, 64);      // seg pairs
        p += __shfl_xor(p, 2, 64);
        if (seg == 0) hs[k * EMB + cT] = fmaxf(p + btc, 0.f);
    }
    __syncthreads();

    // stage QKVS: 2 matrices per thread — 1 h-read feeds 2 dot products
    int c = tid & 127;
    int m2 = tid >> 8;            // 0: K+V, 1: Q+S
    int g2 = (tid >> 7) & 1;
    const float *Wa, *ba, *Wb, *bb;
    if (m2 == 0) { Wa = Wk; ba = bk; Wb = Wv; bb = bv; }
    else         { Wa = Wq; ba = bq; Wb = Ws; bb = bs; }
    float wa[EMB], wb[EMB];       // 64 weight regs — r13 showed 128 spills, 64 fits
    #pragma unroll
    for (int f = 0; f < EMB; ++f) { wa[f] = Wa[f * HC + c]; wb[f] = Wb[f * HC + c]; }
    float ba_ = ba[c], bb_ = bb[c];
    for (int k = g2; k < QNPB; k += 2) {
        const float4* h4 = (const float4*)(hs + k * EMB);
        float sa = ba_, sb = bb_;
        #pragma unroll
        for (int f4 = 0; f4 < EMB / 4; ++f4) {
            float4 hv = h4[f4];
            sa += hv.x * wa[4*f4] + hv.y * wa[4*f4+1] + hv.z * wa[4*f4+2] + hv.w * wa[4*f4+3];
            sb += hv.x * wb[4*f4] + hv.y * wb[4*f4+1] + hv.z * wb[4*f4+2] + hv.w * wb[4*f4+3];
        }
        size_t n = node0 + k;
        if (m2 == 0) kvu[n * 128 + c] = pkh2(sa, sb);
        else { Qh[n * HC + c] = (_Float16)sa; Out[n * HC + c] = sb; }
    }
}

// ------- edge attention: fp16 Q + merged 16B edge record + fp16 KV gather ------------
__global__ __launch_bounds__(256) void edge_attn_kernel(const int* __restrict__ row_ptr,
        const uint4* __restrict__ edges,
        const float* __restrict__ We,
        const _Float16* __restrict__ Qh, const uint2* __restrict__ kvp,
        float2* __restrict__ Out) {
    int n = blockIdx.x * 4 + (threadIdx.x >> 6);   // grid*4 == NN exactly
    int lane = threadIdx.x & 63;
    int ch0 = 2 * lane, ch1 = 2 * lane + 1;
    float we0[4], we1[4];
    #pragma unroll
    for (int d = 0; d < 4; ++d) { we0[d] = We[d * HC + ch0]; we1[d] = We[d * HC + ch1]; }
    float2 q = h2f2(((const unsigned int*)Qh)[(size_t)n * 64 + lane]);
    int start = row_ptr[n], end = row_ptr[n + 1];
    float z = 0.f, acc0 = 0.f, acc1 = 0.f;
    const float SC = 0.17677669529663687f;  // 1/sqrt(32)
    int i = start;
    for (; i + 1 < end; i += 2) {
        uint4 rA = edges[i], rB = edges[i + 1];                  // wave-uniform 16B
        int sA = (int)rA.x, sB = (int)rB.x;
        sA = sA < 0 ? 0 : (sA >= NN ? NN - 1 : sA);
        sB = sB < 0 ? 0 : (sB >= NN ? NN - 1 : sB);
        uint2 kvA = kvp[(size_t)sA * 64 + lane];                 // k0,v0,k1,v1 fp16
        uint2 kvB = kvp[(size_t)sB * 64 + lane];
        float2 eAxy = h2f2(rA.y), eAzw = h2f2(rA.z);
        float2 eBxy = h2f2(rB.y), eBzw = h2f2(rB.z);
        float eA0 = eAxy.x * we0[0] + eAxy.y * we0[1] + eAzw.x * we0[2] + eAzw.y * we0[3];
        float eA1 = eAxy.x * we1[0] + eAxy.y * we1[1] + eAzw.x * we1[2] + eAzw.y * we1[3];
        float eB0 = eBxy.x * we0[0] + eBxy.y * we0[1] + eBzw.x * we0[2] + eBzw.y * we0[3];
        float eB1 = eBxy.x * we1[0] + eBxy.y * we1[1] + eBzw.x * we1[2] + eBzw.y * we1[3];
        float2 kvA0 = h2f2(kvA.x), kvA1 = h2f2(kvA.y);           // (k,v) ch0 / ch1
        float2 kvB0 = h2f2(kvB.x), kvB1 = h2f2(kvB.y);
        float pA = q.x * (kvA0.x + eA0) + q.y * (kvA1.x + eA1);
        float pB = q.x * (kvB0.x + eB0) + q.y * (kvB1.x + eB1);
        #pragma unroll
        for (int off = 1; off < 16; off <<= 1) {                 // 16-lane head groups
            pA += __shfl_xor(pA, off, 64);
            pB += __shfl_xor(pB, off, 64);
        }
        float xA = __expf(pA * SC), xB = __expf(pB * SC);
        z += xA + xB;
        acc0 += xA * (kvA0.y + eA0) + xB * (kvB0.y + eB0);
        acc1 += xA * (kvA1.y + eA1) + xB * (kvB1.y + eB1);
    }
    if (i < end) {
        uint4 r = edges[i];
        int s = (int)r.x;
        s = s < 0 ? 0 : (s >= NN ? NN - 1 : s);
        uint2 kv = kvp[(size_t)s * 64 + lane];
        float2 exy = h2f2(r.y), ezw = h2f2(r.z);
        float e0 = exy.x * we0[0] + exy.y * we0[1] + ezw.x * we0[2] + ezw.y * we0[3];
        float e1 = exy.x * we1[0] + exy.y * we1[1] + ezw.x * we1[2] + ezw.y * we1[3];
        float2 kv0 = h2f2(kv.x), kv1 = h2f2(kv.y);
        float p = q.x * (kv0.x + e0) + q.y * (kv1.x + e1);
        #pragma unroll
        for (int off = 1; off < 16; off <<= 1) p += __shfl_xor(p, off, 64);
        float x = __expf(p * SC);
        z += x;
        acc0 += x * (kv0.y + e0);
        acc1 += x * (kv1.y + e1);
    }
    float inv = 1.f / (z + 1e-16f);
    size_t oi = (size_t)n * 64 + lane;
    float2 o = Out[oi];
    o.x += acc0 * inv;
    o.y += acc1 * inv;
    Out[oi] = o;
}

// ---- fused final transform + MLP head, register weights (round-11 stage T) ----------
__global__ __launch_bounds__(512) void head2_kernel(const float* __restrict__ Outb,
        const float* __restrict__ Wt, const float* __restrict__ bt,
        const float* __restrict__ W1, const float* __restrict__ b1,
        const float* __restrict__ W2, const float* __restrict__ b2,
        const float* __restrict__ W3, const float* __restrict__ b3,
        float* __restrict__ out) {
    __shared__ __align__(16) float os[QNPB * HC];   // 25.6 KB; reused as d1s
    __shared__ __align__(16) float hs[QNPB * EMB];  // 6.4 KB
    __shared__ __align__(16) float d2s[QNPB * 64];  // 12.8 KB
    float* d1s = os;                     // alias: os dead once hs is built
    int tid = threadIdx.x;
    int node0 = blockIdx.x * QNPB;
    int g = tid >> 7;                    // 4 node-groups (2 waves each)

    {   // float4 staging copy
        const float4* src4 = (const float4*)(Outb + (size_t)node0 * HC);
        float4* dst4 = (float4*)os;
        for (int i = tid; i < QNPB * HC / 4; i += 512) dst4[i] = src4[i];
    }

    // stage T
    int cT = (tid & 127) >> 2, seg = tid & 3;
    float wt[32];
    #pragma unroll
    for (int j = 0; j < 32; ++j) wt[j] = Wt[(seg * 32 + j) * EMB + cT];
    float btc = bt[cT];
    __syncthreads();
    for (int k = g; k < QNPB; k += 4) {
        float p = 0.f;
        const float4* r4 = (const float4*)(os + k * HC + seg * 32);
        #pragma unroll
        for (int j4 = 0; j4 < 8; ++j4) {
            float4 rv = r4[j4];
            p += rv.x * wt[4 * j4] + rv.y * wt[4 * j4 + 1]
               + rv.z * wt[4 * j4 + 2] + rv.w * wt[4 * j4 + 3];
        }
        p += __shfl_xor(p, 1, 64);
        p += __shfl_xor(p, 2, 64);
        if (seg == 0) hs[k * EMB + cT] = fmaxf(p + btc, 0.f);
    }
    __syncthreads();

    // stage 1: d1 = relu(b1 + h @ W1)
    int c1 = tid & 127;
    float w1[32];
    #pragma unroll
    for (int f = 0; f < 32; ++f) w1[f] = W1[f * DENSE + c1];
    float b1c = b1[c1];
    const float4* hs4 = (const float4*)hs;
    for (int k = g; k < QNPB; k += 4) {
        float s = b1c;
        #pragma unroll
        for (int f4 = 0; f4 < 8; ++f4) {
            float4 hv = hs4[k * 8 + f4];
            s += hv.x * w1[4 * f4] + hv.y * w1[4 * f4 + 1]
               + hv.z * w1[4 * f4 + 2] + hv.w * w1[4 * f4 + 3];
        }
        d1s[k * DENSE + c1] = fmaxf(s, 0.f);
    }
    __syncthreads();

    // stage 2: d2 = relu(b2 + d1 @ W2)
    int c2 = (tid & 127) >> 1, hh = tid & 1;
    float w2[64];
    #pragma unroll
    for (int j = 0; j < 64; ++j) w2[j] = W2[(hh * 64 + j) * 64 + c2];
    float b2c = b2[c2];
    for (int k = g; k < QNPB; k += 4) {
        float p = 0.f;
        const float4* r4 = (const float4*)(d1s + k * DENSE + hh * 64);
        #pragma unroll
        for (int j4 = 0; j4 < 16; ++j4) {
            float4 rv = r4[j4];
            p += rv.x * w2[4 * j4] + rv.y * w2[4 * j4 + 1]
               + rv.z * w2[4 * j4 + 2] + rv.w * w2[4 * j4 + 3];
        }
        p += __shfl_xor(p, 1, 64);
        if (hh == 0) d2s[k * 64 + c2] = fmaxf(p + b2c, 0.f);
    }
    __syncthreads();

    // stage 3
    int w = tid >> 6, lane = tid & 63;
    float w3r = W3[lane];
    float b3r = b3[0];
    for (int k = w; k < QNPB; k += 8) {
        float t = d2s[k * 64 + lane] * w3r;
        #pragma unroll
        for (int off = 1; off < 64; off <<= 1) t += __shfl_xor(t, off, 64);
        if (lane == 0) out[node0 + k] = 1.f / (1.f + __expf(-(t + b3r)));
    }
}

extern "C" void kernel_launch(void* const* d_in, const int* in_sizes, int n_in,
                              void* d_out, int out_size, void* d_ws, size_t ws_size,
                              hipStream_t stream) {
    const float* x   = (const float*)d_in[0];
    const int*   ei  = (const int*)d_in[1];    // [2,E]: src=ei, dst=ei+E
    const float* ea  = (const float*)d_in[2];
    const float* Wq0 = (const float*)d_in[3];  const float* bq0 = (const float*)d_in[4];
    const float* Wk0 = (const float*)d_in[5];  const float* bk0 = (const float*)d_in[6];
    const float* Wv0 = (const float*)d_in[7];  const float* bv0 = (const float*)d_in[8];
    const float* We0 = (const float*)d_in[9];
    const float* Ws0 = (const float*)d_in[10]; const float* bs0 = (const float*)d_in[11];
    const float* Wt0 = (const float*)d_in[12]; const float* bt0 = (const float*)d_in[13];
    const float* WqL = (const float*)d_in[14]; const float* bqL = (const float*)d_in[15];
    const float* WkL = (const float*)d_in[16]; const float* bkL = (const float*)d_in[17];
    const float* WvL = (const float*)d_in[18]; const float* bvL = (const float*)d_in[19];
    const float* WeL = (const float*)d_in[20];
    const float* WsL = (const float*)d_in[21]; const float* bsL = (const float*)d_in[22];
    const float* WtL = (const float*)d_in[23]; const float* btL = (const float*)d_in[24];
    const float* W1  = (const float*)d_in[25]; const float* b1  = (const float*)d_in[26];
    const float* W2  = (const float*)d_in[27]; const float* b2  = (const float*)d_in[28];
    const float* W3  = (const float*)d_in[29]; const float* b3  = (const float*)d_in[30];
    float* out = (float*)d_out;

    char* ws = (char*)d_ws;
    size_t off = 0;
    auto alloc = [&](size_t bytes) -> void* {
        void* p = ws + off; off = (off + bytes + 255) & ~(size_t)255; return p;
    };
    int*          cursor  = (int*)         alloc((size_t)NN * 4);
    int*          row_ptr = (int*)         alloc((size_t)(NN + 1) * 4);
    int*          bsum    = (int*)         alloc((size_t)SBLK * 4);
    uint4*        edges   = (uint4*)       alloc((size_t)EE * 16);
    _Float16*     Qh      = (_Float16*)    alloc((size_t)NN * HC * 2);
    unsigned int* kvu     = (unsigned int*)alloc((size_t)NN * HC * 4);  // (k,v) packed
    float*        Outb    = (float*)       alloc((size_t)NN * HC * 4);
    // total ~77 MB

    // ---- CSR by dst (edge_index shared by all 3 conv layers) ----
    hipMemsetAsync(cursor, 0, (size_t)NN * 4, stream);
    hist_kernel<<<(EE + 255) / 256, 256, 0, stream>>>(ei + EE, cursor);
    scan1_kernel<<<SBLK, 1024, 0, stream>>>(cursor, row_ptr, bsum);
    scan3_kernel<<<SBLK, 1024, 0, stream>>>(row_ptr, cursor, bsum);   // scan2 folded in
    scatter_kernel<<<(EE + 255) / 256, 256, 0, stream>>>(ei, ei + EE, ea, cursor, edges);

    const uint2* kvp = (const uint2*)kvu;
    float2* Out2 = (float2*)Outb;

    // ---- layer 0 ----
    qkvs0_kernel<<<NN / QNPB, 512, 0, stream>>>(x, Wq0, bq0, Wk0, bk0, Wv0, bv0,
                                                Ws0, bs0, Qh, kvu, Outb);
    edge_attn_kernel<<<NN / 4, 256, 0, stream>>>(row_ptr, edges, We0, Qh, kvp, Out2);

    // ---- layer 1 ----
    ftq_kernel<<<NN / QNPB, 512, 0, stream>>>(Wt0, bt0,
        WqL, bqL, WkL, bkL, WvL, bvL, WsL, bsL, Qh, kvu, Outb);
    edge_attn_kernel<<<NN / 4, 256, 0, stream>>>(row_ptr, edges, WeL, Qh, kvp, Out2);

    // ---- layer 2 ----
    ftq_kernel<<<NN / QNPB, 512, 0, stream>>>(WtL, btL,
        WqL + EMB * HC, bqL + HC, WkL + EMB * HC, bkL + HC,
        WvL + EMB * HC, bvL + HC, WsL + EMB * HC, bsL + HC, Qh, kvu, Outb);
    edge_attn_kernel<<<NN / 4, 256, 0, stream>>>(row_ptr, edges,
        WeL + EDIM * HC, Qh, kvp, Out2);

    // ---- fused final transform + register-weight MLP head ----
    head2_kernel<<<NN / QNPB, 512, 0, stream>>>(Outb, WtL + (size_t)HC * EMB, btL + EMB,
                                                W1, b1, W2, b2, W3, b3, out);
}

// Round 18
// 622.118 us; speedup vs baseline: 1.0239x; 1.0239x over previous
//
#include <hip/hip_runtime.h>

#define NN 50000
#define EE 800000
#define FIN 16
#define EDIM 4
#define EMB 32
#define NH 4
#define HC 128          // EMB*NH
#define NL 2
#define DENSE 128
#define QNPB 50         // nodes per qkvs/ftq/head block (50000 = 1000 * 50)
#define SBLK 49         // scan blocks: ceil(50000/1024)

// unpack two packed fp16 -> float2
__device__ __forceinline__ float2 h2f2(unsigned int u) {
    union { unsigned int u; _Float16 h[2]; } c; c.u = u;
    return make_float2((float)c.h[0], (float)c.h[1]);
}
__device__ __forceinline__ unsigned int pkh2(float a, float b) {
    union { unsigned int u; _Float16 h[2]; } c;
    c.h[0] = (_Float16)a; c.h[1] = (_Float16)b; return c.u;
}

// ---------------- CSR build ----------------
__global__ void hist_kernel(const int* __restrict__ dst, int* __restrict__ counts) {
    int e = blockIdx.x * blockDim.x + threadIdx.x;
    if (e < EE) atomicAdd(&counts[dst[e]], 1);
}

__global__ __launch_bounds__(1024) void scan1_kernel(const int* __restrict__ cursor,
                                                     int* __restrict__ row_ptr,
                                                     int* __restrict__ bsum) {
    __shared__ int wsum[16];
    __shared__ int wpre[17];
    int tid = threadIdx.x, lane = tid & 63, wid = tid >> 6;
    int i = blockIdx.x * 1024 + tid;
    int v = (i < NN) ? cursor[i] : 0;
    int incl = v;
    #pragma unroll
    for (int off = 1; off < 64; off <<= 1) {
        int t = __shfl_up(incl, off, 64);
        if (lane >= off) incl += t;
    }
    if (lane == 63) wsum[wid] = incl;
    __syncthreads();
    if (tid == 0) {
        int acc = 0;
        #pragma unroll
        for (int w = 0; w < 16; ++w) { wpre[w] = acc; acc += wsum[w]; }
        wpre[16] = acc;
    }
    __syncthreads();
    if (i < NN) row_ptr[i] = wpre[wid] + incl - v;
    if (tid == 0) bsum[blockIdx.x] = wpre[16];
}

// scan3 with scan2 folded in: every block re-scans the 49 block sums in its first wave
__global__ __launch_bounds__(1024) void scan3_kernel(int* __restrict__ row_ptr,
                                                     int* __restrict__ cursor,
                                                     const int* __restrict__ bsum) {
    __shared__ int boff_s;
    __shared__ int total_s;
    int tid = threadIdx.x;
    if (tid < 64) {
        int v = (tid < SBLK) ? bsum[tid] : 0;
        int incl = v;
        #pragma unroll
        for (int off = 1; off < 64; off <<= 1) {
            int u = __shfl_up(incl, off, 64);
            if (tid >= off) incl += u;
        }
        if (tid == (int)blockIdx.x) boff_s = incl - v;
        if (tid == 63) total_s = incl;
    }
    __syncthreads();
    int i = blockIdx.x * 1024 + tid;
    if (i < NN) {
        int r = row_ptr[i] + boff_s;
        row_ptr[i] = r;
        cursor[i] = r;
    }
    if (blockIdx.x == 0 && tid == 0) row_ptr[NN] = total_s;   // == EE
}

// edge record: x=src, y=ea fp16(0,1), z=ea fp16(2,3), w=unused — one 16B store
__global__ void scatter_kernel(const int* __restrict__ src, const int* __restrict__ dst,
                               const float* __restrict__ ea, int* __restrict__ cursor,
                               uint4* __restrict__ edges) {
    int e = blockIdx.x * blockDim.x + threadIdx.x;
    if (e >= EE) return;
    int d = dst[e];
    int pos = atomicAdd(&cursor[d], 1);
    float4 q = *reinterpret_cast<const float4*>(ea + (size_t)e * 4);
    uint4 rec;
    rec.x = (unsigned int)src[e];
    rec.y = pkh2(q.x, q.y);
    rec.z = pkh2(q.z, q.w);
    rec.w = 0u;
    edges[pos] = rec;
}

// ------- layer-0 projections: Q fp16, K/V packed fp16, skip into Out; f4 LDS --------
__global__ __launch_bounds__(512) void qkvs0_kernel(const float* __restrict__ x,
        const float* __restrict__ Wq, const float* __restrict__ bq,
        const float* __restrict__ Wk, const float* __restrict__ bk,
        const float* __restrict__ Wv, const float* __restrict__ bv,
        const float* __restrict__ Ws, const float* __restrict__ bs,
        _Float16* __restrict__ Qh, _Float16* __restrict__ kvh,
        float* __restrict__ Out) {
    __shared__ __align__(16) float hs[QNPB * FIN];
    int tid = threadIdx.x;
    int m = tid >> 7, c = tid & 127;
    const float* W; const float* b;
    switch (m) {
        case 0:  W = Wq; b = bq; break;
        case 1:  W = Wk; b = bk; break;
        case 2:  W = Wv; b = bv; break;
        default: W = Ws; b = bs; break;
    }
    float w[FIN];
    #pragma unroll
    for (int f = 0; f < FIN; ++f) w[f] = W[f * HC + c];
    float bias = b[c];
    int node0 = blockIdx.x * QNPB;
    {   // float4 staging copy
        const float4* src4 = (const float4*)(x + (size_t)node0 * FIN);
        float4* dst4 = (float4*)hs;
        for (int i = tid; i < QNPB * FIN / 4; i += 512) dst4[i] = src4[i];
    }
    __syncthreads();
    const float4* hs4 = (const float4*)hs;
    for (int k = 0; k < QNPB; ++k) {
        float s = bias;
        #pragma unroll
        for (int f4 = 0; f4 < FIN / 4; ++f4) {
            float4 hv = hs4[k * (FIN / 4) + f4];
            s += hv.x * w[4 * f4] + hv.y * w[4 * f4 + 1]
               + hv.z * w[4 * f4 + 2] + hv.w * w[4 * f4 + 3];
        }
        size_t n = node0 + k;
        if      (m == 0) Qh[n * HC + c] = (_Float16)s;
        else if (m == 1) kvh[n * 256 + 2 * c] = (_Float16)s;
        else if (m == 2) kvh[n * 256 + 2 * c + 1] = (_Float16)s;
        else             Out[n * HC + c] = s;
    }
}

// ---- fused transform + projections, register-cached Wt (round-11 stage T) ----------
__global__ __launch_bounds__(512) void ftq_kernel(const float* __restrict__ Wt,
        const float* __restrict__ bt,
        const float* __restrict__ Wq, const float* __restrict__ bq,
        const float* __restrict__ Wk, const float* __restrict__ bk,
        const float* __restrict__ Wv, const float* __restrict__ bv,
        const float* __restrict__ Ws, const float* __restrict__ bs,
        _Float16* __restrict__ Qh, _Float16* __restrict__ kvh,
        float* __restrict__ Out) {
    __shared__ __align__(16) float os[QNPB * HC];   // 25.6 KB
    __shared__ __align__(16) float hs[QNPB * EMB];  // 6.4 KB
    int tid = threadIdx.x;
    int node0 = blockIdx.x * QNPB;
    int g = tid >> 7;                   // 4 node-groups (2 waves each)

    {   // float4 staging copy
        const float4* src4 = (const float4*)(Out + (size_t)node0 * HC);
        float4* dst4 = (float4*)os;
        for (int i = tid; i < QNPB * HC / 4; i += 512) dst4[i] = src4[i];
    }

    // stage T: h = relu(bt + Out @ Wt). thread (g, cT=(tid&127)>>2, seg=tid&3)
    int cT = (tid & 127) >> 2, seg = tid & 3;
    float wt[32];
    #pragma unroll
    for (int j = 0; j < 32; ++j) wt[j] = Wt[(seg * 32 + j) * EMB + cT];
    float btc = bt[cT];
    __syncthreads();
    for (int k = g; k < QNPB; k += 4) {
        float p = 0.f;
        const float4* r4 = (const float4*)(os + k * HC + seg * 32);
        #pragma unroll
        for (int j4 = 0; j4 < 8; ++j4) {
            float4 rv = r4[j4];
            p += rv.x * wt[4 * j4] + rv.y * wt[4 * j4 + 1]
               + rv.z * wt[4 * j4 + 2] + rv.w * wt[4 * j4 + 3];
        }
        p += __shfl_xor(p, 1, 64);      // seg pairs
        p += __shfl_xor(p, 2, 64);
        if (seg == 0) hs[k * EMB + cT] = fmaxf(p + btc, 0.f);
    }
    __syncthreads();

    // stage QKVS: weights in registers (EMB=32/thread), float4 h reads
    int m = tid >> 7, c = tid & 127;
    const float* W; const float* b;
    switch (m) {
        case 0:  W = Wq; b = bq; break;
        case 1:  W = Wk; b = bk; break;
        case 2:  W = Wv; b = bv; break;
        default: W = Ws; b = bs; break;
    }
    float w[EMB];
    #pragma unroll
    for (int f = 0; f < EMB; ++f) w[f] = W[f * HC + c];
    float bias = b[c];
    const float4* hs4 = (const float4*)hs;
    for (int k = 0; k < QNPB; ++k) {
        float s = bias;
        #pragma unroll
        for (int f4 = 0; f4 < EMB / 4; ++f4) {
            float4 hv = hs4[k * (EMB / 4) + f4];
            s += hv.x * w[4 * f4] + hv.y * w[4 * f4 + 1]
               + hv.z * w[4 * f4 + 2] + hv.w * w[4 * f4 + 3];
        }
        size_t n = node0 + k;
        if      (m == 0) Qh[n * HC + c] = (_Float16)s;
        else if (m == 1) kvh[n * 256 + 2 * c] = (_Float16)s;
        else if (m == 2) kvh[n * 256 + 2 * c + 1] = (_Float16)s;
        else             Out[n * HC + c] = s;
    }
}

// ------- edge attention: fp16 Q + merged 16B edge record + fp16 KV gather ------------
__global__ __launch_bounds__(256) void edge_attn_kernel(const int* __restrict__ row_ptr,
        const uint4* __restrict__ edges,
        const float* __restrict__ We,
        const _Float16* __restrict__ Qh, const uint2* __restrict__ kvp,
        float2* __restrict__ Out) {
    int n = blockIdx.x * 4 + (threadIdx.x >> 6);   // grid*4 == NN exactly
    int lane = threadIdx.x & 63;
    int ch0 = 2 * lane, ch1 = 2 * lane + 1;
    float we0[4], we1[4];
    #pragma unroll
    for (int d = 0; d < 4; ++d) { we0[d] = We[d * HC + ch0]; we1[d] = We[d * HC + ch1]; }
    float2 q = h2f2(((const unsigned int*)Qh)[(size_t)n * 64 + lane]);
    int start = row_ptr[n], end = row_ptr[n + 1];
    float z = 0.f, acc0 = 0.f, acc1 = 0.f;
    const float SC = 0.17677669529663687f;  // 1/sqrt(32)
    int i = start;
    for (; i + 1 < end; i += 2) {
        uint4 rA = edges[i], rB = edges[i + 1];                  // wave-uniform 16B
        int sA = (int)rA.x, sB = (int)rB.x;
        sA = sA < 0 ? 0 : (sA >= NN ? NN - 1 : sA);
        sB = sB < 0 ? 0 : (sB >= NN ? NN - 1 : sB);
        uint2 kvA = kvp[(size_t)sA * 64 + lane];                 // k0,v0,k1,v1 fp16
        uint2 kvB = kvp[(size_t)sB * 64 + lane];
        float2 eAxy = h2f2(rA.y), eAzw = h2f2(rA.z);
        float2 eBxy = h2f2(rB.y), eBzw = h2f2(rB.z);
        float eA0 = eAxy.x * we0[0] + eAxy.y * we0[1] + eAzw.x * we0[2] + eAzw.y * we0[3];
        float eA1 = eAxy.x * we1[0] + eAxy.y * we1[1] + eAzw.x * we1[2] + eAzw.y * we1[3];
        float eB0 = eBxy.x * we0[0] + eBxy.y * we0[1] + eBzw.x * we0[2] + eBzw.y * we0[3];
        float eB1 = eBxy.x * we1[0] + eBxy.y * we1[1] + eBzw.x * we1[2] + eBzw.y * we1[3];
        float2 kvA0 = h2f2(kvA.x), kvA1 = h2f2(kvA.y);           // (k,v) ch0 / ch1
        float2 kvB0 = h2f2(kvB.x), kvB1 = h2f2(kvB.y);
        float pA = q.x * (kvA0.x + eA0) + q.y * (kvA1.x + eA1);
        float pB = q.x * (kvB0.x + eB0) + q.y * (kvB1.x + eB1);
        #pragma unroll
        for (int off = 1; off < 16; off <<= 1) {                 // 16-lane head groups
            pA += __shfl_xor(pA, off, 64);
            pB += __shfl_xor(pB, off, 64);
        }
        float xA = __expf(pA * SC), xB = __expf(pB * SC);
        z += xA + xB;
        acc0 += xA * (kvA0.y + eA0) + xB * (kvB0.y + eB0);
        acc1 += xA * (kvA1.y + eA1) + xB * (kvB1.y + eB1);
    }
    if (i < end) {
        uint4 r = edges[i];
        int s = (int)r.x;
        s = s < 0 ? 0 : (s >= NN ? NN - 1 : s);
        uint2 kv = kvp[(size_t)s * 64 + lane];
        float2 exy = h2f2(r.y), ezw = h2f2(r.z);
        float e0 = exy.x * we0[0] + exy.y * we0[1] + ezw.x * we0[2] + ezw.y * we0[3];
        float e1 = exy.x * we1[0] + exy.y * we1[1] + ezw.x * we1[2] + ezw.y * we1[3];
        float2 kv0 = h2f2(kv.x), kv1 = h2f2(kv.y);
        float p = q.x * (kv0.x + e0) + q.y * (kv1.x + e1);
        #pragma unroll
        for (int off = 1; off < 16; off <<= 1) p += __shfl_xor(p, off, 64);
        float x = __expf(p * SC);
        z += x;
        acc0 += x * (kv0.y + e0);
        acc1 += x * (kv1.y + e1);
    }
    float inv = 1.f / (z + 1e-16f);
    size_t oi = (size_t)n * 64 + lane;
    float2 o = Out[oi];
    o.x += acc0 * inv;
    o.y += acc1 * inv;
    Out[oi] = o;
}

// ---- fused final transform + MLP head, register weights (round-11 stage T) ----------
__global__ __launch_bounds__(512) void head2_kernel(const float* __restrict__ Outb,
        const float* __restrict__ Wt, const float* __restrict__ bt,
        const float* __restrict__ W1, const float* __restrict__ b1,
        const float* __restrict__ W2, const float* __restrict__ b2,
        const float* __restrict__ W3, const float* __restrict__ b3,
        float* __restrict__ out) {
    __shared__ __align__(16) float os[QNPB * HC];   // 25.6 KB; reused as d1s
    __shared__ __align__(16) float hs[QNPB * EMB];  // 6.4 KB
    __shared__ __align__(16) float d2s[QNPB * 64];  // 12.8 KB
    float* d1s = os;                     // alias: os dead once hs is built
    int tid = threadIdx.x;
    int node0 = blockIdx.x * QNPB;
    int g = tid >> 7;                    // 4 node-groups (2 waves each)

    {   // float4 staging copy
        const float4* src4 = (const float4*)(Outb + (size_t)node0 * HC);
        float4* dst4 = (float4*)os;
        for (int i = tid; i < QNPB * HC / 4; i += 512) dst4[i] = src4[i];
    }

    // stage T
    int cT = (tid & 127) >> 2, seg = tid & 3;
    float wt[32];
    #pragma unroll
    for (int j = 0; j < 32; ++j) wt[j] = Wt[(seg * 32 + j) * EMB + cT];
    float btc = bt[cT];
    __syncthreads();
    for (int k = g; k < QNPB; k += 4) {
        float p = 0.f;
        const float4* r4 = (const float4*)(os + k * HC + seg * 32);
        #pragma unroll
        for (int j4 = 0; j4 < 8; ++j4) {
            float4 rv = r4[j4];
            p += rv.x * wt[4 * j4] + rv.y * wt[4 * j4 + 1]
               + rv.z * wt[4 * j4 + 2] + rv.w * wt[4 * j4 + 3];
        }
        p += __shfl_xor(p, 1, 64);
        p += __shfl_xor(p, 2, 64);
        if (seg == 0) hs[k * EMB + cT] = fmaxf(p + btc, 0.f);
    }
    __syncthreads();

    // stage 1: d1 = relu(b1 + h @ W1)
    int c1 = tid & 127;
    float w1[32];
    #pragma unroll
    for (int f = 0; f < 32; ++f) w1[f] = W1[f * DENSE + c1];
    float b1c = b1[c1];
    const float4* hs4 = (const float4*)hs;
    for (int k = g; k < QNPB; k += 4) {
        float s = b1c;
        #pragma unroll
        for (int f4 = 0; f4 < 8; ++f4) {
            float4 hv = hs4[k * 8 + f4];
            s += hv.x * w1[4 * f4] + hv.y * w1[4 * f4 + 1]
               + hv.z * w1[4 * f4 + 2] + hv.w * w1[4 * f4 + 3];
        }
        d1s[k * DENSE + c1] = fmaxf(s, 0.f);
    }
    __syncthreads();

    // stage 2: d2 = relu(b2 + d1 @ W2)
    int c2 = (tid & 127) >> 1, hh = tid & 1;
    float w2[64];
    #pragma unroll
    for (int j = 0; j < 64; ++j) w2[j] = W2[(hh * 64 + j) * 64 + c2];
    float b2c = b2[c2];
    for (int k = g; k < QNPB; k += 4) {
        float p = 0.f;
        const float4* r4 = (const float4*)(d1s + k * DENSE + hh * 64);
        #pragma unroll
        for (int j4 = 0; j4 < 16; ++j4) {
            float4 rv = r4[j4];
            p += rv.x * w2[4 * j4] + rv.y * w2[4 * j4 + 1]
               + rv.z * w2[4 * j4 + 2] + rv.w * w2[4 * j4 + 3];
        }
        p += __shfl_xor(p, 1, 64);
        if (hh == 0) d2s[k * 64 + c2] = fmaxf(p + b2c, 0.f);
    }
    __syncthreads();

    // stage 3
    int w = tid >> 6, lane = tid & 63;
    float w3r = W3[lane];
    float b3r = b3[0];
    for (int k = w; k < QNPB; k += 8) {
        float t = d2s[k * 64 + lane] * w3r;
        #pragma unroll
        for (int off = 1; off < 64; off <<= 1) t += __shfl_xor(t, off, 64);
        if (lane == 0) out[node0 + k] = 1.f / (1.f + __expf(-(t + b3r)));
    }
}

extern "C" void kernel_launch(void* const* d_in, const int* in_sizes, int n_in,
                              void* d_out, int out_size, void* d_ws, size_t ws_size,
                              hipStream_t stream) {
    const float* x   = (const float*)d_in[0];
    const int*   ei  = (const int*)d_in[1];    // [2,E]: src=ei, dst=ei+E
    const float* ea  = (const float*)d_in[2];
    const float* Wq0 = (const float*)d_in[3];  const float* bq0 = (const float*)d_in[4];
    const float* Wk0 = (const float*)d_in[5];  const float* bk0 = (const float*)d_in[6];
    const float* Wv0 = (const float*)d_in[7];  const float* bv0 = (const float*)d_in[8];
    const float* We0 = (const float*)d_in[9];
    const float* Ws0 = (const float*)d_in[10]; const float* bs0 = (const float*)d_in[11];
    const float* Wt0 = (const float*)d_in[12]; const float* bt0 = (const float*)d_in[13];
    const float* WqL = (const float*)d_in[14]; const float* bqL = (const float*)d_in[15];
    const float* WkL = (const float*)d_in[16]; const float* bkL = (const float*)d_in[17];
    const float* WvL = (const float*)d_in[18]; const float* bvL = (const float*)d_in[19];
    const float* WeL = (const float*)d_in[20];
    const float* WsL = (const float*)d_in[21]; const float* bsL = (const float*)d_in[22];
    const float* WtL = (const float*)d_in[23]; const float* btL = (const float*)d_in[24];
    const float* W1  = (const float*)d_in[25]; const float* b1  = (const float*)d_in[26];
    const float* W2  = (const float*)d_in[27]; const float* b2  = (const float*)d_in[28];
    const float* W3  = (const float*)d_in[29]; const float* b3  = (const float*)d_in[30];
    float* out = (float*)d_out;

    char* ws = (char*)d_ws;
    size_t off = 0;
    auto alloc = [&](size_t bytes) -> void* {
        void* p = ws + off; off = (off + bytes + 255) & ~(size_t)255; return p;
    };
    int*      cursor  = (int*)     alloc((size_t)NN * 4);
    int*      row_ptr = (int*)     alloc((size_t)(NN + 1) * 4);
    int*      bsum    = (int*)     alloc((size_t)SBLK * 4);
    uint4*    edges   = (uint4*)   alloc((size_t)EE * 16);
    _Float16* Qh      = (_Float16*)alloc((size_t)NN * HC * 2);
    _Float16* kvh     = (_Float16*)alloc((size_t)NN * HC * 2 * 2);  // (k,v) interleaved
    float*    Outb    = (float*)   alloc((size_t)NN * HC * 4);
    // total ~77 MB

    // ---- CSR by dst (edge_index shared by all 3 conv layers) ----
    hipMemsetAsync(cursor, 0, (size_t)NN * 4, stream);
    hist_kernel<<<(EE + 255) / 256, 256, 0, stream>>>(ei + EE, cursor);
    scan1_kernel<<<SBLK, 1024, 0, stream>>>(cursor, row_ptr, bsum);
    scan3_kernel<<<SBLK, 1024, 0, stream>>>(row_ptr, cursor, bsum);   // scan2 folded in
    scatter_kernel<<<(EE + 255) / 256, 256, 0, stream>>>(ei, ei + EE, ea, cursor, edges);

    const uint2* kvp = (const uint2*)kvh;
    float2* Out2 = (float2*)Outb;

    // ---- layer 0 ----
    qkvs0_kernel<<<NN / QNPB, 512, 0, stream>>>(x, Wq0, bq0, Wk0, bk0, Wv0, bv0,
                                                Ws0, bs0, Qh, kvh, Outb);
    edge_attn_kernel<<<NN / 4, 256, 0, stream>>>(row_ptr, edges, We0, Qh, kvp, Out2);

    // ---- layer 1 ----
    ftq_kernel<<<NN / QNPB, 512, 0, stream>>>(Wt0, bt0,
        WqL, bqL, WkL, bkL, WvL, bvL, WsL, bsL, Qh, kvh, Outb);
    edge_attn_kernel<<<NN / 4, 256, 0, stream>>>(row_ptr, edges, WeL, Qh, kvp, Out2);

    // ---- layer 2 ----
    ftq_kernel<<<NN / QNPB, 512, 0, stream>>>(WtL, btL,
        WqL + EMB * HC, bqL + HC, WkL + EMB * HC, bkL + HC,
        WvL + EMB * HC, bvL + HC, WsL + EMB * HC, bsL + HC, Qh, kvh, Outb);
    edge_attn_kernel<<<NN / 4, 256, 0, stream>>>(row_ptr, edges,
        WeL + EDIM * HC, Qh, kvp, Out2);

    // ---- fused final transform + register-weight MLP head ----
    head2_kernel<<<NN / QNPB, 512, 0, stream>>>(Outb, WtL + (size_t)HC * EMB, btL + EMB,
                                                W1, b1, W2, b2, W3, b3, out);
}